// Round 1
// baseline (59.965 us; speedup 1.0000x reference)
//
#include <hip/hip_runtime.h>

#define VOCAB 32000
#define EDIM  128
#define QN    32
#define DN    256
#define DTILE 64
#define NK    11
#define LDSP  (EDIM + 4)   // +4 floats pad -> 2-way bank aliasing (free)

// ---------------- inv-norm precompute: one wave per vocab row ----------------
__global__ __launch_bounds__(256) void invnorm_kernel(const float* __restrict__ emb,
                                                      float* __restrict__ invn) {
    int lane = threadIdx.x & 63;
    int row  = blockIdx.x * 4 + (threadIdx.x >> 6);
    if (row >= VOCAB) return;
    const float2* p = (const float2*)(emb + (size_t)row * EDIM);
    float2 v = p[lane];                       // 2 elems/lane * 64 lanes = 128
    float s = v.x * v.x + v.y * v.y;
    #pragma unroll
    for (int off = 32; off; off >>= 1) s += __shfl_xor(s, off);
    if (lane == 0) invn[row] = 1.0f / sqrtf(s);
}

#define DOT4(acc, a, v)                                                        \
    acc = fmaf((a).x, (v).x, acc);                                             \
    acc = fmaf((a).y, (v).y, acc);                                             \
    acc = fmaf((a).z, (v).z, acc);                                             \
    acc = fmaf((a).w, (v).w, acc);

// ---------------- main: one block per batch ----------------
__global__ __launch_bounds__(256) void knrm_main(const int* __restrict__ qtok,
                                                 const int* __restrict__ dtok,
                                                 const float* __restrict__ emb,
                                                 const float* __restrict__ invn,
                                                 const float* __restrict__ fcw,
                                                 float* __restrict__ out) {
    __shared__ __align__(16) float qn[QN][LDSP];
    __shared__ __align__(16) float dt[DTILE][LDSP];
    __shared__ float dscale[DTILE];
    __shared__ float qmask[QN];
    __shared__ float accs[QN][NK];
    __shared__ float red[4];

    // mu chain: 1.0, 0.9, then -0.2 steps (f64 chain rounds to these f32 values)
    const float MU[NK] = {1.0f, 0.9f, 0.7f, 0.5f, 0.3f, 0.1f,
                          -0.1f, -0.3f, -0.5f, -0.7f, -0.9f};
    // CC[k] = -1/(2*sigma^2): sigma0=1e-4 -> -5e7 ; sigma=0.1 -> -50
    const float CC[NK] = {-5.0e7f, -50.0f, -50.0f, -50.0f, -50.0f, -50.0f,
                          -50.0f, -50.0f, -50.0f, -50.0f, -50.0f};
    const float INV_SQRT_2PI = 0.3989422804014327f;

    int b   = blockIdx.x;
    int tid = threadIdx.x;
    const int* qt  = qtok + b * QN;
    const int* dtk = dtok + b * DN;

    // ---- stage normalized queries: 32 rows, 8 threads/row, 16 floats each ----
    {
        int r = tid >> 3, c = tid & 7;
        int tok = qt[r];
        float inv = invn[tok];
        const float4* src = (const float4*)(emb + (size_t)tok * EDIM);
        float4* dst = (float4*)&qn[r][0];
        #pragma unroll
        for (int j = 0; j < 4; ++j) {
            float4 v = src[c * 4 + j];
            v.x *= inv; v.y *= inv; v.z *= inv; v.w *= inv;
            dst[c * 4 + j] = v;
        }
        if (c == 0) qmask[r] = (tok > 0) ? 1.0f : 0.0f;
    }

    int qg = tid >> 4;   // 0..15 -> q rows {2qg, 2qg+1}
    int dg = tid & 15;   // 0..15 -> d rows {4dg .. 4dg+3} within tile

    float kacc[2][NK];
    #pragma unroll
    for (int qq = 0; qq < 2; ++qq)
        #pragma unroll
        for (int k = 0; k < NK; ++k) kacc[qq][k] = 0.0f;

    for (int t0 = 0; t0 < DN; t0 += DTILE) {
        __syncthreads();   // previous tile fully consumed (and q staged on iter 0)
        // ---- stage normalized doc tile: 64 rows in 2 passes of 32 ----
        #pragma unroll
        for (int pass = 0; pass < 2; ++pass) {
            int r = pass * 32 + (tid >> 3), c = tid & 7;
            int tok = dtk[t0 + r];
            float inv = invn[tok];
            const float4* src = (const float4*)(emb + (size_t)tok * EDIM);
            float4* dst = (float4*)&dt[r][0];
            #pragma unroll
            for (int j = 0; j < 4; ++j) {
                float4 v = src[c * 4 + j];
                v.x *= inv; v.y *= inv; v.z *= inv; v.w *= inv;
                dst[c * 4 + j] = v;
            }
            if (c == 0) dscale[r] = (tok > 0) ? INV_SQRT_2PI : 0.0f;
        }
        __syncthreads();

        // ---- 2q x 4d register-tile dot products over E=128 ----
        const float4* q0 = (const float4*)&qn[qg * 2 + 0][0];
        const float4* q1 = (const float4*)&qn[qg * 2 + 1][0];
        const float4* d0 = (const float4*)&dt[dg * 4 + 0][0];
        const float4* d1 = (const float4*)&dt[dg * 4 + 1][0];
        const float4* d2 = (const float4*)&dt[dg * 4 + 2][0];
        const float4* d3 = (const float4*)&dt[dg * 4 + 3][0];

        float dot[2][4];
        #pragma unroll
        for (int qq = 0; qq < 2; ++qq)
            #pragma unroll
            for (int i = 0; i < 4; ++i) dot[qq][i] = 0.0f;

        #pragma unroll 8
        for (int e = 0; e < EDIM / 4; ++e) {
            float4 a0 = q0[e];
            float4 a1 = q1[e];
            float4 v0 = d0[e];
            float4 v1 = d1[e];
            float4 v2 = d2[e];
            float4 v3 = d3[e];
            DOT4(dot[0][0], a0, v0); DOT4(dot[0][1], a0, v1);
            DOT4(dot[0][2], a0, v2); DOT4(dot[0][3], a0, v3);
            DOT4(dot[1][0], a1, v0); DOT4(dot[1][1], a1, v1);
            DOT4(dot[1][2], a1, v2); DOT4(dot[1][3], a1, v3);
        }

        // ---- 11 Gaussian kernels per tm value; d-mask & 1/sqrt(2pi) folded ----
        #pragma unroll
        for (int i = 0; i < 4; ++i) {
            float sc = dscale[dg * 4 + i];
            #pragma unroll
            for (int qq = 0; qq < 2; ++qq) {
                float t = dot[qq][i];
                #pragma unroll
                for (int k = 0; k < NK; ++k) {
                    float u = t - MU[k];
                    kacc[qq][k] = fmaf(__expf(u * u * CC[k]), sc, kacc[qq][k]);
                }
            }
        }
    }

    // ---- reduce over the 16 d-groups (all within one wave: lanes differ in dg) ----
    #pragma unroll
    for (int off = 1; off < 16; off <<= 1)
        #pragma unroll
        for (int qq = 0; qq < 2; ++qq)
            #pragma unroll
            for (int k = 0; k < NK; ++k)
                kacc[qq][k] += __shfl_xor(kacc[qq][k], off);

    if (dg == 0) {
        #pragma unroll
        for (int qq = 0; qq < 2; ++qq)
            #pragma unroll
            for (int k = 0; k < NK; ++k)
                accs[qg * 2 + qq][k] = kacc[qq][k];
    }
    __syncthreads();

    // ---- log-pool + weighted sum over (q,k): out[b] ----
    float total = 0.0f;
    for (int i = tid; i < QN * NK; i += 256) {
        int q = i / NK, k = i - q * NK;
        total += fcw[k] * logf(fmaxf(accs[q][k], 1e-10f)) * qmask[q];
    }
    #pragma unroll
    for (int off = 32; off; off >>= 1) total += __shfl_xor(total, off);
    if ((tid & 63) == 0) red[tid >> 6] = total;
    __syncthreads();
    if (tid == 0) out[b] = red[0] + red[1] + red[2] + red[3];
}

extern "C" void kernel_launch(void* const* d_in, const int* in_sizes, int n_in,
                              void* d_out, int out_size, void* d_ws, size_t ws_size,
                              hipStream_t stream) {
    const int*   qtok = (const int*)d_in[0];
    const int*   dtok = (const int*)d_in[1];
    const float* emb  = (const float*)d_in[2];
    const float* fcw  = (const float*)d_in[3];
    float* out  = (float*)d_out;
    float* invn = (float*)d_ws;   // 32000 floats = 128 KB scratch

    invnorm_kernel<<<(VOCAB + 3) / 4, 256, 0, stream>>>(emb, invn);

    int B = in_sizes[0] / QN;     // 512
    knrm_main<<<B, 256, 0, stream>>>(qtok, dtok, emb, invn, fcw, out);
}